// Round 9
// baseline (986.227 us; speedup 1.0000x reference)
//
#include <hip/hip_runtime.h>

// VQ-VAE vector quantizer, MI355X round 9.
// = round 8 (pre-split swizzle-baked planes, spill-free 6-chain bf16x3 MFMA)
// with TRIPLE-buffered staging + counted s_waitcnt vmcnt(6) + raw s_barrier:
// loads stay in flight across barriers (T4), removing the 2-phase vmcnt(0)
// drain that capped r8 at MfmaUtil 57%. Tile 128x128, 3x48KB LDS buffers.
// Operand values and MFMA chain order bit-identical to r6/r7/r8 -> decisions
// unchanged; risk + r4-bit-identical rescan proven (absmax 0 three rounds).
// z: [2,512,8,32,32] fp32 ; emb: [8192,512] fp32
// out: z_q_ste (8388608 f32) | vq_loss (1 f32) | indices (16384 f32)

constexpr int KCB = 8192;
constexpr int CD  = 512;
constexpr int SD  = 8192;
constexpr int NB  = 2;
constexpr int NR  = NB * SD;                    // 16384
constexpr long ZQ_ELEMS = (long)NB * CD * SD;   // 8388608

constexpr size_t WS_CNT   = 64;
constexpr size_t WS_KEYS  = 128;       // u64 keys[16384]     -> 131200
constexpr size_t WS_RISK  = 139264;    // u32 rminKey[16384]  -> 204800
constexpr size_t WS_IDX   = 212992;    // int idxArr[16384]   -> 278528
constexpr size_t WS_LIST  = 286720;    // int list[16384]     -> 352256
constexpr size_t WS_ZNORM = 360448;    // f32 znorm[16384]    -> 425984
constexpr size_t WS_ENORM = 425984;    // f32 enorm[8192]     -> 458752
constexpr size_t WS_EMBT  = 458752;    // f32 embt            -> 17235968
constexpr size_t WS_ZH    = 17235968;  // bf16 z planes, tiled
constexpr size_t WS_ZM    = 34013184;
constexpr size_t WS_ZL    = 50790400;
constexpr size_t WS_EH    = 67567616;  // bf16 e planes, tiled
constexpr size_t WS_EM    = 75956224;
constexpr size_t WS_EL    = 84344832;  // -> 92733440 (~88.5MB)

#define RISK_EPS 2.0e-7f
#define WINDOW   1.3e-4f

typedef __attribute__((ext_vector_type(8))) short short8;
typedef __attribute__((ext_vector_type(4))) float f32x4;

__device__ __forceinline__ unsigned int fkey(float f) {
  unsigned int b = __float_as_uint(f);
  return (b & 0x80000000u) ? ~b : (b | 0x80000000u);
}
__device__ __forceinline__ float unfkey(unsigned int u) {
  return (u & 0x80000000u) ? __uint_as_float(u ^ 0x80000000u)
                           : __uint_as_float(~u);
}
__device__ __forceinline__ ushort bf16_rne(float f, float* back) {
  unsigned int u = __float_as_uint(f);
  ushort h = (ushort)((u + 0x7FFFu + ((u >> 16) & 1u)) >> 16);
  *back = __uint_as_float((unsigned int)h << 16);
  return h;
}
__device__ __forceinline__ void gload16(const void* g, void* l) {
  __builtin_amdgcn_global_load_lds(
      (const __attribute__((address_space(1))) unsigned int*)g,
      (__attribute__((address_space(3))) unsigned int*)l, 16, 0, 0);
}

// ---- znorm[n] = fp32(sum_c z[n][c]^2), fp64 accumulate ----
__global__ __launch_bounds__(256) void k_znorm(const float* __restrict__ z,
                                               float* __restrict__ znorm) {
  int n0 = blockIdx.x * 256;
  int b = n0 / SD, s0 = n0 % SD;
  const float* zp = z + (size_t)b * CD * SD + s0 + threadIdx.x;
  double a = 0.0;
  #pragma unroll 8
  for (int c = 0; c < CD; ++c) {
    double v = (double)zp[(size_t)c * SD];
    a = fma(v, v, a);
  }
  znorm[n0 + threadIdx.x] = (float)a;
}

// ---- enorm[k] ----
__global__ __launch_bounds__(256) void k_enorm(const float* __restrict__ emb,
                                               float* __restrict__ enorm) {
  int row  = blockIdx.x * 4 + (threadIdx.x >> 6);
  int lane = threadIdx.x & 63;
  const float4* p = (const float4*)(emb + (size_t)row * CD);
  float4 a = p[lane * 2], b = p[lane * 2 + 1];
  float s = a.x*a.x + a.y*a.y + a.z*a.z + a.w*a.w
          + b.x*b.x + b.y*b.y + b.z*b.z + b.w*b.w;
  #pragma unroll
  for (int off = 32; off; off >>= 1) s += __shfl_down(s, off);
  if (lane == 0) enorm[row] = s;
}

// ---- emb_t[c][k] = emb[k][c] (feeds the r4-identical rescan) ----
__global__ __launch_bounds__(256) void k_transpose(const float* __restrict__ emb,
                                                   float* __restrict__ embt) {
  __shared__ float t[64][65];
  int bk = blockIdx.x & 127, bc = blockIdx.x >> 7;
  int k0 = bk * 64, c0 = bc * 64;
  int t4 = threadIdx.x & 15, tq = threadIdx.x >> 4;
  #pragma unroll
  for (int p = 0; p < 4; ++p) {
    int kk = p * 16 + tq;
    float4 v = *(const float4*)(emb + (size_t)(k0 + kk) * CD + c0 + 4 * t4);
    t[kk][4*t4+0] = v.x; t[kk][4*t4+1] = v.y; t[kk][4*t4+2] = v.z; t[kk][4*t4+3] = v.w;
  }
  __syncthreads();
  #pragma unroll
  for (int p = 0; p < 4; ++p) {
    int cc = p * 16 + tq;
    float4 v;
    v.x = t[4*t4+0][cc]; v.y = t[4*t4+1][cc]; v.z = t[4*t4+2][cc]; v.w = t[4*t4+3][cc];
    *(float4*)(embt + (size_t)(c0 + cc) * KCB + k0 + 4 * t4) = v;
  }
}

// Tiled plane layout (r7-proven): tile (rt,ct) = 256 rows x 32 cols, 8192
// ushorts at (rt*16+ct)*8192. Element (r,c) at r*32 + ((c>>3)^((r>>1)&3))*8
// + (c&7): wave64 b128 fragment reads are bank-conflict-free while
// global_load_lds stages linearly (swizzle baked into global layout).

// ---- z [b][c][s] -> zh/zm/zl tiled planes ----
__global__ __launch_bounds__(256) void k_zsplit(const float* __restrict__ z,
                                                ushort* __restrict__ zh,
                                                ushort* __restrict__ zm,
                                                ushort* __restrict__ zl) {
  __shared__ float t[32][257];
  int rt = blockIdx.x >> 4, ct = blockIdx.x & 15;
  int n0 = rt * 256;
  int b = n0 >> 13, s0 = n0 & (SD - 1);
  const float* zp = z + (size_t)b * CD * SD + (size_t)(ct * 32) * SD + s0;
  #pragma unroll 4
  for (int c = 0; c < 32; ++c)
    t[c][threadIdx.x] = zp[(size_t)c * SD + threadIdx.x];
  __syncthreads();
  size_t tbase = ((size_t)rt * 16 + ct) * 8192;
  #pragma unroll
  for (int p = 0; p < 4; ++p) {
    int slot = p * 256 + threadIdx.x;
    int r = slot >> 2, cs = slot & 3;
    int csw = cs ^ ((r >> 1) & 3);
    union { ushort u[8]; int4 v; } ph, pm, pl;
    #pragma unroll
    for (int j = 0; j < 8; ++j) {
      float f = t[cs * 8 + j][r];
      float fh, fm, fl2;
      ph.u[j] = bf16_rne(f, &fh);
      float r1 = f - fh;
      pm.u[j] = bf16_rne(r1, &fm);
      float r2 = r1 - fm;
      pl.u[j] = bf16_rne(r2, &fl2);
    }
    size_t off = tbase + (size_t)r * 32 + csw * 8;
    *(int4*)(zh + off) = ph.v;
    *(int4*)(zm + off) = pm.v;
    *(int4*)(zl + off) = pl.v;
  }
}

// ---- emb [k][c] -> eh/em/el tiled planes ----
__global__ __launch_bounds__(256) void k_esplit(const float* __restrict__ emb,
                                                ushort* __restrict__ eh,
                                                ushort* __restrict__ em,
                                                ushort* __restrict__ el) {
  __shared__ float t[32][257];
  int rt = blockIdx.x >> 4, ct = blockIdx.x & 15;
  int k0 = rt * 256;
  #pragma unroll 4
  for (int i = 0; i < 32; ++i) {
    int idx = i * 256 + threadIdx.x;
    int r = idx >> 5, c = idx & 31;
    t[c][r] = emb[(size_t)(k0 + r) * CD + ct * 32 + c];
  }
  __syncthreads();
  size_t tbase = ((size_t)rt * 16 + ct) * 8192;
  #pragma unroll
  for (int p = 0; p < 4; ++p) {
    int slot = p * 256 + threadIdx.x;
    int r = slot >> 2, cs = slot & 3;
    int csw = cs ^ ((r >> 1) & 3);
    union { ushort u[8]; int4 v; } ph, pm, pl;
    #pragma unroll
    for (int j = 0; j < 8; ++j) {
      float f = t[cs * 8 + j][r];
      float fh, fm, fl2;
      ph.u[j] = bf16_rne(f, &fh);
      float r1 = f - fh;
      pm.u[j] = bf16_rne(r1, &fm);
      float r2 = r1 - fm;
      pl.u[j] = bf16_rne(r2, &fl2);
    }
    size_t off = tbase + (size_t)r * 32 + csw * 8;
    *(int4*)(eh + off) = ph.v;
    *(int4*)(em + off) = pm.v;
    *(int4*)(el + off) = pl.v;
  }
}

// ---- MFMA distance kernel: triple-buffer, counted vmcnt, raw s_barrier ----
// 256 blocks x 512 thr (8 waves, 2Mx4N on 128x128 tile). Block: 128 m-rows x
// one khalf (4096 n in 32 it x 128). LDS: 3 x 49152 B buffers = 147456 B.
// Per buffer: Ah|Am|Al|Bh|Bm|Bl, 8192 B each. 6 gload16/thread/stage.
__global__ __launch_bounds__(512, 2) void k_dist_mfma(
    const ushort* __restrict__ zh, const ushort* __restrict__ zm,
    const ushort* __restrict__ zl,
    const ushort* __restrict__ eh, const ushort* __restrict__ em,
    const ushort* __restrict__ el,
    const float* __restrict__ enorm, const float* __restrict__ znorm,
    unsigned long long* __restrict__ keys, unsigned int* __restrict__ riskArr) {
  extern __shared__ __align__(16) char smem[];

  int tid  = threadIdx.x;
  int lane = tid & 63;
  int wid  = tid >> 6;
  int wm = wid >> 2, wn = wid & 3;       // 2M x 4N wave grid
  int lk = lane >> 4, lc = lane & 15;

  // bijective XCD swizzle (256 % 8 == 0)
  int bid = (int)blockIdx.x;
  int swz = (bid & 7) * 32 + (bid >> 3);
  int m0    = (swz >> 1) * 128;          // 128 m-blocks
  int khalf = swz & 1;
  int n_rt  = m0 >> 8;
  int ahalf = (m0 >> 7) & 1;

  size_t thr8  = (size_t)tid * 8;        // ushort offset per thread (16B)
  int    tid16 = tid * 16;               // LDS byte offset per thread

  // loop-invariant fragment LDS byte offsets (within one plane region)
  int afo[4], bfo[2];
  #pragma unroll
  for (int mi = 0; mi < 4; ++mi) {
    int rowA = wm * 64 + mi * 16 + lc;
    afo[mi] = rowA * 64 + ((lk ^ ((rowA >> 1) & 3)) << 4);
  }
  #pragma unroll
  for (int ni = 0; ni < 2; ++ni) {
    int rowB = wn * 32 + ni * 16 + lc;
    bfo[ni] = rowB * 64 + ((lk ^ ((rowB >> 1) & 3)) << 4);
  }

  // znorm hoisted (16 VGPR; epilogue then only loads enorm)
  float Aab[16];
  #pragma unroll
  for (int li = 0; li < 16; ++li)
    Aab[li] = znorm[m0 + wm * 64 + (li >> 2) * 16 + lk * 4 + (li & 3)];

  unsigned long long bkey[16];
  float rminv[16];
  #pragma unroll
  for (int li = 0; li < 16; ++li) { bkey[li] = ~0ull; rminv[li] = 3.402823466e38f; }

#define STAGE(s_) do {                                                   \
    int it_ = (s_) >> 4, ks_ = (s_) & 15;                                \
    char* lb_ = smem + ((s_) % 3) * 49152;                               \
    size_t ae_ = (size_t)(n_rt * 16 + ks_) * 8192 + (size_t)ahalf * 4096 \
                 + thr8;                                                 \
    size_t be_ = (size_t)((khalf * 16 + (it_ >> 1)) * 16 + ks_) * 8192   \
                 + (size_t)(it_ & 1) * 4096 + thr8;                      \
    gload16(zh + ae_, lb_ + tid16);                                      \
    gload16(zm + ae_, lb_ + 8192 + tid16);                               \
    gload16(zl + ae_, lb_ + 16384 + tid16);                              \
    gload16(eh + be_, lb_ + 24576 + tid16);                              \
    gload16(em + be_, lb_ + 32768 + tid16);                              \
    gload16(el + be_, lb_ + 40960 + tid16);                              \
  } while (0)

  STAGE(0);
  STAGE(1);

  for (int it = 0; it < 32; ++it) {
    f32x4 acc[4][2];
    #pragma unroll
    for (int mi = 0; mi < 4; ++mi)
      #pragma unroll
      for (int ni = 0; ni < 2; ++ni) {
        f32x4 zz = {0.f, 0.f, 0.f, 0.f};
        acc[mi][ni] = zz;
      }

    for (int ks = 0; ks < 16; ++ks) {
      int s = it * 16 + ks;
      // counted drain: own STAGE(s) retired (STAGE(s+1) stays in flight)
      if (s < 511) asm volatile("s_waitcnt vmcnt(6)" ::: "memory");
      else         asm volatile("s_waitcnt vmcnt(0)" ::: "memory");
      __builtin_amdgcn_s_barrier();          // all waves' STAGE(s) landed
      __builtin_amdgcn_sched_barrier(0);     // no hoist/sink across (rule 18)
      if (s + 2 < 512) STAGE(s + 2);         // overwrite buf freed at s-1

      const char* Cb = smem + (s % 3) * 49152;
      short8 a_h[4], a_m[4], a_l[4];
      #pragma unroll
      for (int mi = 0; mi < 4; ++mi) {
        a_h[mi] = *(const short8*)(Cb + afo[mi]);
        a_m[mi] = *(const short8*)(Cb + 8192 + afo[mi]);
        a_l[mi] = *(const short8*)(Cb + 16384 + afo[mi]);
      }
      #pragma unroll
      for (int ni = 0; ni < 2; ++ni) {
        short8 b_h = *(const short8*)(Cb + 24576 + bfo[ni]);
        short8 b_m = *(const short8*)(Cb + 32768 + bfo[ni]);
        short8 b_l = *(const short8*)(Cb + 40960 + bfo[ni]);
        #pragma unroll
        for (int mi = 0; mi < 4; ++mi)
          acc[mi][ni] = __builtin_amdgcn_mfma_f32_16x16x32_bf16(a_h[mi], b_h, acc[mi][ni], 0, 0, 0);
        #pragma unroll
        for (int mi = 0; mi < 4; ++mi)
          acc[mi][ni] = __builtin_amdgcn_mfma_f32_16x16x32_bf16(a_h[mi], b_m, acc[mi][ni], 0, 0, 0);
        #pragma unroll
        for (int mi = 0; mi < 4; ++mi)
          acc[mi][ni] = __builtin_amdgcn_mfma_f32_16x16x32_bf16(a_m[mi], b_h, acc[mi][ni], 0, 0, 0);
        #pragma unroll
        for (int mi = 0; mi < 4; ++mi)
          acc[mi][ni] = __builtin_amdgcn_mfma_f32_16x16x32_bf16(a_h[mi], b_l, acc[mi][ni], 0, 0, 0);
        #pragma unroll
        for (int mi = 0; mi < 4; ++mi)
          acc[mi][ni] = __builtin_amdgcn_mfma_f32_16x16x32_bf16(a_m[mi], b_m, acc[mi][ni], 0, 0, 0);
        #pragma unroll
        for (int mi = 0; mi < 4; ++mi)
          acc[mi][ni] = __builtin_amdgcn_mfma_f32_16x16x32_bf16(a_l[mi], b_h, acc[mi][ni], 0, 0, 0);
      }
    }

    // per-it epilogue (extra vmem loads only force conservative draining)
    int N0 = khalf * 4096 + it * 128;
    #pragma unroll
    for (int ni = 0; ni < 2; ++ni) {
      int col = N0 + wn * 32 + ni * 16 + lc;
      float en = enorm[col];
      #pragma unroll
      for (int mi = 0; mi < 4; ++mi) {
        #pragma unroll
        for (int r = 0; r < 4; ++r) {
          int li = mi * 4 + r;
          float ab = Aab[li] + en;
          float q  = -2.0f * acc[mi][ni][r];
          float sv = ab + q;
          float bvv = sv - ab;               // Fast2Sum: exact
          float t   = q - bvv;               // rounding residual
          unsigned int su = __float_as_uint(sv);
          float ulp = __uint_as_float(su & 0x7f800000u) * 1.1920929e-7f;
          bool risky = (0.5f * ulp - fabsf(t)) < RISK_EPS;
          if (((su & 0x7fffffu) == 0u) && (t < 0.f))
            risky |= ((0.25f * ulp + t) < RISK_EPS);
          unsigned long long key =
              ((unsigned long long)fkey(sv) << 32) | (unsigned int)col;
          if (key < bkey[li]) bkey[li] = key;
          if (risky && sv < rminv[li]) rminv[li] = sv;
        }
      }
    }
  }
#undef STAGE

  // block reduction (reuse LDS; full drain via __syncthreads)
  __syncthreads();
  unsigned long long* red = (unsigned long long*)smem;   // [128][64]
  #pragma unroll
  for (int li = 0; li < 16; ++li) {
    int row = wm * 64 + (li >> 2) * 16 + lk * 4 + (li & 3);
    red[row * 64 + wn * 16 + lc] = bkey[li];
  }
  __syncthreads();
  if (tid < 128) {
    unsigned long long mn = ~0ull;
    #pragma unroll 4
    for (int i = 0; i < 64; ++i) {
      unsigned long long v = red[tid * 64 + i];
      if (v < mn) mn = v;
    }
    atomicMin(&keys[m0 + tid], mn);
  }
  __syncthreads();
  unsigned int* red2 = (unsigned int*)smem;
  #pragma unroll
  for (int li = 0; li < 16; ++li) {
    int row = wm * 64 + (li >> 2) * 16 + lk * 4 + (li & 3);
    red2[row * 64 + wn * 16 + lc] = fkey(rminv[li]);
  }
  __syncthreads();
  if (tid < 128) {
    unsigned int mn = 0xFFFFFFFFu;
    #pragma unroll 4
    for (int i = 0; i < 64; ++i) {
      unsigned int v = red2[tid * 64 + i];
      if (v < mn) mn = v;
    }
    atomicMin(&riskArr[m0 + tid], mn);
  }
}

// ---- resolve: window test vs FINAL global min ----
__global__ __launch_bounds__(256) void k_resolve(const unsigned long long* __restrict__ keys,
                                                 const unsigned int* __restrict__ riskArr,
                                                 int* __restrict__ idxArr,
                                                 int* __restrict__ list,
                                                 unsigned int* __restrict__ cnt) {
  int row = blockIdx.x * 256 + threadIdx.x;
  unsigned long long kk = keys[row];
  idxArr[row] = (int)(kk & 0xffffffffull) & (KCB - 1);
  float smin = unfkey((unsigned int)(kk >> 32));
  float rmin = unfkey(riskArr[row]);          // NaN when no risky candidate
  if (rmin <= smin + WINDOW) {
    unsigned int pos = atomicAdd(cnt, 1u);
    list[pos & (NR - 1)] = row;
  }
}

// ---- rescan: bit-identical r4 fp32 path, 4-way ILP ----
__global__ __launch_bounds__(256) void k_rescan(const float* __restrict__ z,
                                                const float* __restrict__ embt,
                                                const float* __restrict__ enorm,
                                                const float* __restrict__ znorm,
                                                const int* __restrict__ list,
                                                const unsigned int* __restrict__ cnt,
                                                int* __restrict__ idxArr) {
  __shared__ float zs[512];
  __shared__ unsigned long long rk[256];
  int tid = threadIdx.x;
  unsigned int nr = *cnt;
  if (nr > (unsigned int)NR) nr = NR;
  for (unsigned int li = blockIdx.x; li < nr; li += gridDim.x) {
    int row = list[li] & (NR - 1);
    int b = row >> 13, s = row & (SD - 1);
    const float* zp = z + (size_t)b * CD * SD + s;
    zs[tid]       = zp[(size_t)tid * SD];
    zs[tid + 256] = zp[(size_t)(tid + 256) * SD];
    __syncthreads();
    float A = znorm[row];
    unsigned long long best = ~0ull;
    #pragma unroll 1
    for (int g = 0; g < 8; ++g) {
      int ka = tid + g * 1024;
      float a0 = 0.f, a1 = 0.f, a2 = 0.f, a3 = 0.f;
      #pragma unroll 8
      for (int c = 0; c < CD; ++c) {          // ascending c: r4's exact order
        const float* ep = embt + (size_t)c * KCB + ka;
        float zc = zs[c];
        a0 = fmaf(zc, ep[0],   a0);
        a1 = fmaf(zc, ep[256], a1);
        a2 = fmaf(zc, ep[512], a2);
        a3 = fmaf(zc, ep[768], a3);
      }
      float av[4] = {a0, a1, a2, a3};
      #pragma unroll
      for (int jj = 0; jj < 4; ++jj) {
        int k = ka + jj * 256;
        float d = (A + enorm[k]) - 2.0f * av[jj];   // identical to r4
        unsigned long long key =
            ((unsigned long long)fkey(d) << 32) | (unsigned int)k;
        if (key < best) best = key;
      }
    }
    rk[tid] = best;
    __syncthreads();
    for (int s2 = 128; s2; s2 >>= 1) {
      if (tid < s2 && rk[tid + s2] < rk[tid]) rk[tid] = rk[tid + s2];
      __syncthreads();
    }
    if (tid == 0) idxArr[row] = (int)(rk[0] & 0xffffffffull) & (KCB - 1);
    __syncthreads();
  }
}

// ---- gather + STE + mse partial ----
__global__ __launch_bounds__(256) void k_gather(const float* __restrict__ z,
                                                const float* __restrict__ emb,
                                                const int* __restrict__ idxArr,
                                                float* __restrict__ out,
                                                double* __restrict__ acc) {
  __shared__ float q[16][516];
  __shared__ int   idxs[16];
  __shared__ float wpart[4];
  int tid = threadIdx.x;
  int n0 = blockIdx.x * 16;
  int b = n0 / SD, s0 = n0 % SD;
  if (tid < 16) {
    int idx = idxArr[n0 + tid] & (KCB - 1);
    idxs[tid] = idx;
    out[ZQ_ELEMS + 1 + n0 + tid] = (float)idx;
  }
  __syncthreads();
  int row = tid >> 4, c4 = (tid & 15) * 4;
  const float* esrc = emb + (size_t)idxs[row] * CD;
  #pragma unroll
  for (int p = 0; p < 8; ++p) {
    int c = c4 + p * 64;
    *(float4*)&q[row][c] = *(const float4*)(esrc + c);
  }
  __syncthreads();
  int si = tid & 15, cq = tid >> 4;
  float sum = 0.f;
  const float* zrd = z   + (size_t)b * CD * SD + s0 + si;
  float*       owr = out + (size_t)b * CD * SD + s0 + si;
  #pragma unroll
  for (int j = 0; j < 32; ++j) {
    int c = cq + 16 * j;
    float zv = zrd[(size_t)c * SD];
    float qv = q[si][c];
    float d = qv - zv;
    sum += d * d;
    owr[(size_t)c * SD] = zv + (qv - zv);
  }
  #pragma unroll
  for (int off = 32; off; off >>= 1) sum += __shfl_down(sum, off);
  if ((tid & 63) == 0) wpart[tid >> 6] = sum;
  __syncthreads();
  if (tid == 0) {
    double t = (double)wpart[0] + (double)wpart[1] + (double)wpart[2] + (double)wpart[3];
    atomicAdd(acc, t);
  }
}

__global__ void k_loss(const double* __restrict__ acc, float* __restrict__ out) {
  out[ZQ_ELEMS] = (float)(1.25 * (*acc) / (double)ZQ_ELEMS);
}

extern "C" void kernel_launch(void* const* d_in, const int* in_sizes, int n_in,
                              void* d_out, int out_size, void* d_ws, size_t ws_size,
                              hipStream_t stream) {
  const float* z   = (const float*)d_in[0];
  const float* emb = (const float*)d_in[1];
  float* out = (float*)d_out;
  double*             acc   = (double*)d_ws;
  unsigned int*       cnt   = (unsigned int*)((char*)d_ws + WS_CNT);
  unsigned long long* keys  = (unsigned long long*)((char*)d_ws + WS_KEYS);
  unsigned int*       risk  = (unsigned int*)((char*)d_ws + WS_RISK);
  int*                idxA  = (int*)((char*)d_ws + WS_IDX);
  int*                list  = (int*)((char*)d_ws + WS_LIST);
  float*              znorm = (float*)((char*)d_ws + WS_ZNORM);
  float*              enorm = (float*)((char*)d_ws + WS_ENORM);
  float*              embt  = (float*)((char*)d_ws + WS_EMBT);
  ushort* zh = (ushort*)((char*)d_ws + WS_ZH);
  ushort* zm = (ushort*)((char*)d_ws + WS_ZM);
  ushort* zl = (ushort*)((char*)d_ws + WS_ZL);
  ushort* eh = (ushort*)((char*)d_ws + WS_EH);
  ushort* em = (ushort*)((char*)d_ws + WS_EM);
  ushort* el = (ushort*)((char*)d_ws + WS_EL);
  (void)in_sizes; (void)n_in; (void)out_size; (void)ws_size;

  hipMemsetAsync(d_ws, 0, 128, stream);                                  // acc+cnt
  hipMemsetAsync((char*)d_ws + WS_KEYS, 0xFF, (size_t)NR * 8, stream);   // keys
  hipMemsetAsync((char*)d_ws + WS_RISK, 0xFF, (size_t)NR * 4, stream);   // rmin keys

  k_znorm    <<<NR / 256, 256, 0, stream>>>(z, znorm);
  k_enorm    <<<KCB / 4, 256, 0, stream>>>(emb, enorm);
  k_transpose<<<(KCB / 64) * (CD / 64), 256, 0, stream>>>(emb, embt);
  k_zsplit   <<<(NR / 256) * 16, 256, 0, stream>>>(z, zh, zm, zl);
  k_esplit   <<<(KCB / 256) * 16, 256, 0, stream>>>(emb, eh, em, el);
  k_dist_mfma<<<256, 512, 147456, stream>>>(zh, zm, zl, eh, em, el,
                                            enorm, znorm, keys, risk);
  k_resolve  <<<NR / 256, 256, 0, stream>>>(keys, risk, idxA, list, cnt);
  k_rescan   <<<256, 256, 0, stream>>>(z, embt, enorm, znorm, list, cnt, idxA);
  k_gather   <<<NR / 16, 256, 0, stream>>>(z, emb, idxA, out, acc);
  k_loss     <<<1, 1, 0, stream>>>(acc, out);
}

// Round 10
// 753.622 us; speedup vs baseline: 1.3086x; 1.3086x over previous
//
#include <hip/hip_runtime.h>

// VQ-VAE vector quantizer, MI355X round 10.
// bf16x2 4-chain MFMA distance GEMM (hh,hm,mh,mm): truncation RMS ~1e-8 is
// below the fp32-accumulation noise (~3e-8) the risk machinery already
// covers -> same RISK_EPS bound, decisions still == r4 (proven epilogue +
// r4-bit-identical rescan). 2/3 the traffic and 2/3 the MFMA of the 6-chain.
// 128x256 tile, TRIPLE-buffered gload_lds staging, counted vmcnt(7), raw
// s_barrier; enorm staged to LDS as uniform 7th load (no VMEM in epilogue).
// z: [2,512,8,32,32] fp32 ; emb: [8192,512] fp32
// out: z_q_ste (8388608 f32) | vq_loss (1 f32) | indices (16384 f32)

constexpr int KCB = 8192;
constexpr int CD  = 512;
constexpr int SD  = 8192;
constexpr int NB  = 2;
constexpr int NR  = NB * SD;                    // 16384
constexpr long ZQ_ELEMS = (long)NB * CD * SD;   // 8388608

constexpr size_t WS_CNT   = 64;
constexpr size_t WS_KEYS  = 128;       // u64 keys[16384]     -> 131200
constexpr size_t WS_RISK  = 139264;    // u32 rminKey[16384]  -> 204800
constexpr size_t WS_IDX   = 212992;    // int idxArr[16384]   -> 278528
constexpr size_t WS_LIST  = 286720;    // int list[16384]     -> 352256
constexpr size_t WS_ZNORM = 360448;    // f32 znorm[16384]    -> 425984
constexpr size_t WS_ENORM = 425984;    // f32 enorm[8192]     -> 458752
constexpr size_t WS_EMBT  = 458752;    // f32 embt            -> 17235968
constexpr size_t WS_ZH    = 17235968;  // bf16 z planes, tiled (16.78MB each)
constexpr size_t WS_ZM    = 34013184;
constexpr size_t WS_EH    = 50790400;  // bf16 e planes, tiled (8.39MB each)
constexpr size_t WS_EM    = 59179008;  // -> 67567616 (~64.4MB)

#define RISK_EPS 2.0e-7f
#define WINDOW   1.3e-4f

// k_dist LDS: 3 buffers x 50176 B: Ah 8K | Am 8K | Bh 16K | Bm 16K | enorm 1K
constexpr int BUFB = 50176;

typedef __attribute__((ext_vector_type(8))) short short8;
typedef __attribute__((ext_vector_type(4))) float f32x4;

__device__ __forceinline__ unsigned int fkey(float f) {
  unsigned int b = __float_as_uint(f);
  return (b & 0x80000000u) ? ~b : (b | 0x80000000u);
}
__device__ __forceinline__ float unfkey(unsigned int u) {
  return (u & 0x80000000u) ? __uint_as_float(u ^ 0x80000000u)
                           : __uint_as_float(~u);
}
__device__ __forceinline__ ushort bf16_rne(float f, float* back) {
  unsigned int u = __float_as_uint(f);
  ushort h = (ushort)((u + 0x7FFFu + ((u >> 16) & 1u)) >> 16);
  *back = __uint_as_float((unsigned int)h << 16);
  return h;
}
__device__ __forceinline__ void gload16(const void* g, void* l) {
  __builtin_amdgcn_global_load_lds(
      (const __attribute__((address_space(1))) unsigned int*)g,
      (__attribute__((address_space(3))) unsigned int*)l, 16, 0, 0);
}

// ---- znorm[n] = fp32(sum_c z[n][c]^2), fp64 accumulate ----
__global__ __launch_bounds__(256) void k_znorm(const float* __restrict__ z,
                                               float* __restrict__ znorm) {
  int n0 = blockIdx.x * 256;
  int b = n0 / SD, s0 = n0 % SD;
  const float* zp = z + (size_t)b * CD * SD + s0 + threadIdx.x;
  double a = 0.0;
  #pragma unroll 8
  for (int c = 0; c < CD; ++c) {
    double v = (double)zp[(size_t)c * SD];
    a = fma(v, v, a);
  }
  znorm[n0 + threadIdx.x] = (float)a;
}

// ---- enorm[k] ----
__global__ __launch_bounds__(256) void k_enorm(const float* __restrict__ emb,
                                               float* __restrict__ enorm) {
  int row  = blockIdx.x * 4 + (threadIdx.x >> 6);
  int lane = threadIdx.x & 63;
  const float4* p = (const float4*)(emb + (size_t)row * CD);
  float4 a = p[lane * 2], b = p[lane * 2 + 1];
  float s = a.x*a.x + a.y*a.y + a.z*a.z + a.w*a.w
          + b.x*b.x + b.y*b.y + b.z*b.z + b.w*b.w;
  #pragma unroll
  for (int off = 32; off; off >>= 1) s += __shfl_down(s, off);
  if (lane == 0) enorm[row] = s;
}

// ---- emb_t[c][k] = emb[k][c] (feeds the r4-identical rescan) ----
__global__ __launch_bounds__(256) void k_transpose(const float* __restrict__ emb,
                                                   float* __restrict__ embt) {
  __shared__ float t[64][65];
  int bk = blockIdx.x & 127, bc = blockIdx.x >> 7;
  int k0 = bk * 64, c0 = bc * 64;
  int t4 = threadIdx.x & 15, tq = threadIdx.x >> 4;
  #pragma unroll
  for (int p = 0; p < 4; ++p) {
    int kk = p * 16 + tq;
    float4 v = *(const float4*)(emb + (size_t)(k0 + kk) * CD + c0 + 4 * t4);
    t[kk][4*t4+0] = v.x; t[kk][4*t4+1] = v.y; t[kk][4*t4+2] = v.z; t[kk][4*t4+3] = v.w;
  }
  __syncthreads();
  #pragma unroll
  for (int p = 0; p < 4; ++p) {
    int cc = p * 16 + tq;
    float4 v;
    v.x = t[4*t4+0][cc]; v.y = t[4*t4+1][cc]; v.z = t[4*t4+2][cc]; v.w = t[4*t4+3][cc];
    *(float4*)(embt + (size_t)(c0 + cc) * KCB + k0 + 4 * t4) = v;
  }
}

// Tiled plane layout (r7-proven): tile (rt,ct) = 256 rows x 32 cols, 8192
// ushorts at (rt*16+ct)*8192. Element (r,c) at r*32 + ((c>>3)^((r>>1)&3))*8
// + (c&7): wave64 b128 fragment reads are bank-conflict-free while
// global_load_lds stages linearly (swizzle baked into global layout).

// ---- z [b][c][s] -> zh/zm tiled planes ----
__global__ __launch_bounds__(256) void k_zsplit(const float* __restrict__ z,
                                                ushort* __restrict__ zh,
                                                ushort* __restrict__ zm) {
  __shared__ float t[32][257];
  int rt = blockIdx.x >> 4, ct = blockIdx.x & 15;
  int n0 = rt * 256;
  int b = n0 >> 13, s0 = n0 & (SD - 1);
  const float* zp = z + (size_t)b * CD * SD + (size_t)(ct * 32) * SD + s0;
  #pragma unroll 4
  for (int c = 0; c < 32; ++c)
    t[c][threadIdx.x] = zp[(size_t)c * SD + threadIdx.x];
  __syncthreads();
  size_t tbase = ((size_t)rt * 16 + ct) * 8192;
  #pragma unroll
  for (int p = 0; p < 4; ++p) {
    int slot = p * 256 + threadIdx.x;
    int r = slot >> 2, cs = slot & 3;
    int csw = cs ^ ((r >> 1) & 3);
    union { ushort u[8]; int4 v; } ph, pm;
    #pragma unroll
    for (int j = 0; j < 8; ++j) {
      float f = t[cs * 8 + j][r];
      float fh, fm;
      ph.u[j] = bf16_rne(f, &fh);
      float r1 = f - fh;
      pm.u[j] = bf16_rne(r1, &fm);
    }
    size_t off = tbase + (size_t)r * 32 + csw * 8;
    *(int4*)(zh + off) = ph.v;
    *(int4*)(zm + off) = pm.v;
  }
}

// ---- emb [k][c] -> eh/em tiled planes ----
__global__ __launch_bounds__(256) void k_esplit(const float* __restrict__ emb,
                                                ushort* __restrict__ eh,
                                                ushort* __restrict__ em) {
  __shared__ float t[32][257];
  int rt = blockIdx.x >> 4, ct = blockIdx.x & 15;
  int k0 = rt * 256;
  #pragma unroll 4
  for (int i = 0; i < 32; ++i) {
    int idx = i * 256 + threadIdx.x;
    int r = idx >> 5, c = idx & 31;
    t[c][r] = emb[(size_t)(k0 + r) * CD + ct * 32 + c];
  }
  __syncthreads();
  size_t tbase = ((size_t)rt * 16 + ct) * 8192;
  #pragma unroll
  for (int p = 0; p < 4; ++p) {
    int slot = p * 256 + threadIdx.x;
    int r = slot >> 2, cs = slot & 3;
    int csw = cs ^ ((r >> 1) & 3);
    union { ushort u[8]; int4 v; } ph, pm;
    #pragma unroll
    for (int j = 0; j < 8; ++j) {
      float f = t[cs * 8 + j][r];
      float fh, fm;
      ph.u[j] = bf16_rne(f, &fh);
      float r1 = f - fh;
      pm.u[j] = bf16_rne(r1, &fm);
    }
    size_t off = tbase + (size_t)r * 32 + csw * 8;
    *(int4*)(eh + off) = ph.v;
    *(int4*)(em + off) = pm.v;
  }
}

// ---- MFMA distance kernel: 128x256 tile, tri-buffer, counted vmcnt(7) ----
// 256 blocks x 512 thr (8 waves, 2Mx4N). Block: 128 m-rows x one khalf
// (4096 n in 16 it x 256). 7 uniform gload16/thread/stage (incl. enorm).
__global__ __launch_bounds__(512, 2) void k_dist_mfma(
    const ushort* __restrict__ zh, const ushort* __restrict__ zm,
    const ushort* __restrict__ eh, const ushort* __restrict__ em,
    const float* __restrict__ enorm_g, const float* __restrict__ znorm,
    unsigned long long* __restrict__ keys, unsigned int* __restrict__ riskArr) {
  extern __shared__ __align__(16) char smem[];

  int tid  = threadIdx.x;
  int lane = tid & 63;
  int wid  = tid >> 6;
  int wm = wid >> 2, wn = wid & 3;       // 2M x 4N wave grid
  int lk = lane >> 4, lc = lane & 15;

  // bijective XCD swizzle (256 % 8 == 0)
  int bid = (int)blockIdx.x;
  int swz = (bid & 7) * 32 + (bid >> 3);
  int m0    = (swz >> 1) * 128;
  int khalf = swz & 1;
  int n_rt  = m0 >> 8;
  int ahalf = (m0 >> 7) & 1;

  size_t thr8  = (size_t)tid * 8;        // ushort offset per thread (16B)
  int    tid16 = tid * 16;
  int    lane16 = lane * 16;

  // loop-invariant fragment LDS byte offsets (within one plane region)
  int afo[4], bfo[4];
  #pragma unroll
  for (int mi = 0; mi < 4; ++mi) {
    int rowA = wm * 64 + mi * 16 + lc;
    afo[mi] = rowA * 64 + ((lk ^ ((rowA >> 1) & 3)) << 4);
  }
  #pragma unroll
  for (int ni = 0; ni < 4; ++ni) {
    int rowB = wn * 64 + ni * 16 + lc;
    bfo[ni] = rowB * 64 + ((lk ^ ((rowB >> 1) & 3)) << 4);
  }

  float Aab[16];
  #pragma unroll
  for (int li = 0; li < 16; ++li)
    Aab[li] = znorm[m0 + wm * 64 + (li >> 2) * 16 + lk * 4 + (li & 3)];

  unsigned long long bkey[16];
  float rminv[16];
  #pragma unroll
  for (int li = 0; li < 16; ++li) { bkey[li] = ~0ull; rminv[li] = 3.402823466e38f; }

  // 7 loads/stage, uniform across all waves (enorm redundantly per wave).
#define STAGE(s_) do {                                                   \
    int it_ = (s_) >> 4, ks_ = (s_) & 15;                                \
    char* lb_ = smem + ((s_) % 3) * BUFB;                                \
    size_t ae_ = (size_t)(n_rt * 16 + ks_) * 8192 + (size_t)ahalf * 4096 \
                 + thr8;                                                 \
    size_t be_ = (size_t)((khalf * 16 + it_) * 16 + ks_) * 8192 + thr8;  \
    gload16(zh + ae_,        lb_ + tid16);                               \
    gload16(zm + ae_,        lb_ + 8192 + tid16);                        \
    gload16(eh + be_,        lb_ + 16384 + tid16);                       \
    gload16(eh + be_ + 4096, lb_ + 24576 + tid16);                       \
    gload16(em + be_,        lb_ + 32768 + tid16);                       \
    gload16(em + be_ + 4096, lb_ + 40960 + tid16);                       \
    gload16(enorm_g + (size_t)(khalf * 4096 + it_ * 256) + lane * 4,     \
            lb_ + 49152 + lane16);                                       \
  } while (0)

  STAGE(0);
  STAGE(1);

  for (int it = 0; it < 16; ++it) {
    f32x4 acc[4][4];
    #pragma unroll
    for (int mi = 0; mi < 4; ++mi)
      #pragma unroll
      for (int ni = 0; ni < 4; ++ni) {
        f32x4 zz = {0.f, 0.f, 0.f, 0.f};
        acc[mi][ni] = zz;
      }

    for (int ks = 0; ks < 16; ++ks) {
      int s = it * 16 + ks;
      // counted drain: own STAGE(s) retired; STAGE(s+1) stays in flight
      if (s + 2 < 256) asm volatile("s_waitcnt vmcnt(7)" ::: "memory");
      else             asm volatile("s_waitcnt vmcnt(0)" ::: "memory");
      __builtin_amdgcn_s_barrier();          // all waves' STAGE(s) landed
      __builtin_amdgcn_sched_barrier(0);     // no hoist across (rule 18)
      if (s + 2 < 256) STAGE(s + 2);         // overwrite buf freed at s-1

      const char* Cb = smem + (s % 3) * BUFB;
      short8 a_h[4], a_m[4];
      #pragma unroll
      for (int mi = 0; mi < 4; ++mi) {
        a_h[mi] = *(const short8*)(Cb + afo[mi]);
        a_m[mi] = *(const short8*)(Cb + 8192 + afo[mi]);
      }
      #pragma unroll
      for (int ni = 0; ni < 4; ++ni) {
        short8 b_h = *(const short8*)(Cb + 16384 + bfo[ni]);
        short8 b_m = *(const short8*)(Cb + 32768 + bfo[ni]);
        #pragma unroll
        for (int mi = 0; mi < 4; ++mi)
          acc[mi][ni] = __builtin_amdgcn_mfma_f32_16x16x32_bf16(a_h[mi], b_h, acc[mi][ni], 0, 0, 0);
        #pragma unroll
        for (int mi = 0; mi < 4; ++mi)
          acc[mi][ni] = __builtin_amdgcn_mfma_f32_16x16x32_bf16(a_h[mi], b_m, acc[mi][ni], 0, 0, 0);
        #pragma unroll
        for (int mi = 0; mi < 4; ++mi)
          acc[mi][ni] = __builtin_amdgcn_mfma_f32_16x16x32_bf16(a_m[mi], b_h, acc[mi][ni], 0, 0, 0);
        #pragma unroll
        for (int mi = 0; mi < 4; ++mi)
          acc[mi][ni] = __builtin_amdgcn_mfma_f32_16x16x32_bf16(a_m[mi], b_m, acc[mi][ni], 0, 0, 0);
      }
    }

    // per-it epilogue; enorm read from LDS (no VMEM -> no pipeline drain)
    int N0 = khalf * 4096 + it * 256;
    const char* Eb = smem + ((it * 16 + 15) % 3) * BUFB + 49152;
    #pragma unroll
    for (int ni = 0; ni < 4; ++ni) {
      int coff = wn * 64 + ni * 16 + lc;
      int col = N0 + coff;
      float en = *(const float*)(Eb + coff * 4);
      #pragma unroll
      for (int mi = 0; mi < 4; ++mi) {
        #pragma unroll
        for (int r = 0; r < 4; ++r) {
          int li = mi * 4 + r;
          float ab = Aab[li] + en;
          float q  = -2.0f * acc[mi][ni][r];
          float sv = ab + q;
          float bvv = sv - ab;               // Fast2Sum: exact
          float t   = q - bvv;               // rounding residual
          unsigned int su = __float_as_uint(sv);
          float ulp = __uint_as_float(su & 0x7f800000u) * 1.1920929e-7f;
          bool risky = (0.5f * ulp - fabsf(t)) < RISK_EPS;
          if (((su & 0x7fffffu) == 0u) && (t < 0.f))
            risky |= ((0.25f * ulp + t) < RISK_EPS);
          unsigned long long key =
              ((unsigned long long)fkey(sv) << 32) | (unsigned int)col;
          if (key < bkey[li]) bkey[li] = key;
          if (risky && sv < rminv[li]) rminv[li] = sv;
        }
      }
    }
  }
#undef STAGE

  // block reduction (reuse LDS)
  __syncthreads();
  unsigned long long* red = (unsigned long long*)smem;   // [128][64] = 64KB
  #pragma unroll
  for (int li = 0; li < 16; ++li) {
    int row = wm * 64 + (li >> 2) * 16 + lk * 4 + (li & 3);
    red[row * 64 + wn * 16 + lc] = bkey[li];
  }
  __syncthreads();
  if (tid < 128) {
    unsigned long long mn = ~0ull;
    #pragma unroll 4
    for (int i = 0; i < 64; ++i) {
      unsigned long long v = red[tid * 64 + i];
      if (v < mn) mn = v;
    }
    atomicMin(&keys[m0 + tid], mn);
  }
  __syncthreads();
  unsigned int* red2 = (unsigned int*)smem;
  #pragma unroll
  for (int li = 0; li < 16; ++li) {
    int row = wm * 64 + (li >> 2) * 16 + lk * 4 + (li & 3);
    red2[row * 64 + wn * 16 + lc] = fkey(rminv[li]);
  }
  __syncthreads();
  if (tid < 128) {
    unsigned int mn = 0xFFFFFFFFu;
    #pragma unroll 4
    for (int i = 0; i < 64; ++i) {
      unsigned int v = red2[tid * 64 + i];
      if (v < mn) mn = v;
    }
    atomicMin(&riskArr[m0 + tid], mn);
  }
}

// ---- resolve: window test vs FINAL global min ----
__global__ __launch_bounds__(256) void k_resolve(const unsigned long long* __restrict__ keys,
                                                 const unsigned int* __restrict__ riskArr,
                                                 int* __restrict__ idxArr,
                                                 int* __restrict__ list,
                                                 unsigned int* __restrict__ cnt) {
  int row = blockIdx.x * 256 + threadIdx.x;
  unsigned long long kk = keys[row];
  idxArr[row] = (int)(kk & 0xffffffffull) & (KCB - 1);
  float smin = unfkey((unsigned int)(kk >> 32));
  float rmin = unfkey(riskArr[row]);          // NaN when no risky candidate
  if (rmin <= smin + WINDOW) {
    unsigned int pos = atomicAdd(cnt, 1u);
    list[pos & (NR - 1)] = row;
  }
}

// ---- rescan: bit-identical r4 fp32 path, 4-way ILP ----
__global__ __launch_bounds__(256) void k_rescan(const float* __restrict__ z,
                                                const float* __restrict__ embt,
                                                const float* __restrict__ enorm,
                                                const float* __restrict__ znorm,
                                                const int* __restrict__ list,
                                                const unsigned int* __restrict__ cnt,
                                                int* __restrict__ idxArr) {
  __shared__ float zs[512];
  __shared__ unsigned long long rk[256];
  int tid = threadIdx.x;
  unsigned int nr = *cnt;
  if (nr > (unsigned int)NR) nr = NR;
  for (unsigned int li = blockIdx.x; li < nr; li += gridDim.x) {
    int row = list[li] & (NR - 1);
    int b = row >> 13, s = row & (SD - 1);
    const float* zp = z + (size_t)b * CD * SD + s;
    zs[tid]       = zp[(size_t)tid * SD];
    zs[tid + 256] = zp[(size_t)(tid + 256) * SD];
    __syncthreads();
    float A = znorm[row];
    unsigned long long best = ~0ull;
    #pragma unroll 1
    for (int g = 0; g < 8; ++g) {
      int ka = tid + g * 1024;
      float a0 = 0.f, a1 = 0.f, a2 = 0.f, a3 = 0.f;
      #pragma unroll 8
      for (int c = 0; c < CD; ++c) {          // ascending c: r4's exact order
        const float* ep = embt + (size_t)c * KCB + ka;
        float zc = zs[c];
        a0 = fmaf(zc, ep[0],   a0);
        a1 = fmaf(zc, ep[256], a1);
        a2 = fmaf(zc, ep[512], a2);
        a3 = fmaf(zc, ep[768], a3);
      }
      float av[4] = {a0, a1, a2, a3};
      #pragma unroll
      for (int jj = 0; jj < 4; ++jj) {
        int k = ka + jj * 256;
        float d = (A + enorm[k]) - 2.0f * av[jj];   // identical to r4
        unsigned long long key =
            ((unsigned long long)fkey(d) << 32) | (unsigned int)k;
        if (key < best) best = key;
      }
    }
    rk[tid] = best;
    __syncthreads();
    for (int s2 = 128; s2; s2 >>= 1) {
      if (tid < s2 && rk[tid + s2] < rk[tid]) rk[tid] = rk[tid + s2];
      __syncthreads();
    }
    if (tid == 0) idxArr[row] = (int)(rk[0] & 0xffffffffull) & (KCB - 1);
    __syncthreads();
  }
}

// ---- gather + STE + mse partial ----
__global__ __launch_bounds__(256) void k_gather(const float* __restrict__ z,
                                                const float* __restrict__ emb,
                                                const int* __restrict__ idxArr,
                                                float* __restrict__ out,
                                                double* __restrict__ acc) {
  __shared__ float q[16][516];
  __shared__ int   idxs[16];
  __shared__ float wpart[4];
  int tid = threadIdx.x;
  int n0 = blockIdx.x * 16;
  int b = n0 / SD, s0 = n0 % SD;
  if (tid < 16) {
    int idx = idxArr[n0 + tid] & (KCB - 1);
    idxs[tid] = idx;
    out[ZQ_ELEMS + 1 + n0 + tid] = (float)idx;
  }
  __syncthreads();
  int row = tid >> 4, c4 = (tid & 15) * 4;
  const float* esrc = emb + (size_t)idxs[row] * CD;
  #pragma unroll
  for (int p = 0; p < 8; ++p) {
    int c = c4 + p * 64;
    *(float4*)&q[row][c] = *(const float4*)(esrc + c);
  }
  __syncthreads();
  int si = tid & 15, cq = tid >> 4;
  float sum = 0.f;
  const float* zrd = z   + (size_t)b * CD * SD + s0 + si;
  float*       owr = out + (size_t)b * CD * SD + s0 + si;
  #pragma unroll
  for (int j = 0; j < 32; ++j) {
    int c = cq + 16 * j;
    float zv = zrd[(size_t)c * SD];
    float qv = q[si][c];
    float d = qv - zv;
    sum += d * d;
    owr[(size_t)c * SD] = zv + (qv - zv);
  }
  #pragma unroll
  for (int off = 32; off; off >>= 1) sum += __shfl_down(sum, off);
  if ((tid & 63) == 0) wpart[tid >> 6] = sum;
  __syncthreads();
  if (tid == 0) {
    double t = (double)wpart[0] + (double)wpart[1] + (double)wpart[2] + (double)wpart[3];
    atomicAdd(acc, t);
  }
}

__global__ void k_loss(const double* __restrict__ acc, float* __restrict__ out) {
  out[ZQ_ELEMS] = (float)(1.25 * (*acc) / (double)ZQ_ELEMS);
}

extern "C" void kernel_launch(void* const* d_in, const int* in_sizes, int n_in,
                              void* d_out, int out_size, void* d_ws, size_t ws_size,
                              hipStream_t stream) {
  const float* z   = (const float*)d_in[0];
  const float* emb = (const float*)d_in[1];
  float* out = (float*)d_out;
  double*             acc   = (double*)d_ws;
  unsigned int*       cnt   = (unsigned int*)((char*)d_ws + WS_CNT);
  unsigned long long* keys  = (unsigned long long*)((char*)d_ws + WS_KEYS);
  unsigned int*       risk  = (unsigned int*)((char*)d_ws + WS_RISK);
  int*                idxA  = (int*)((char*)d_ws + WS_IDX);
  int*                list  = (int*)((char*)d_ws + WS_LIST);
  float*              znorm = (float*)((char*)d_ws + WS_ZNORM);
  float*              enorm = (float*)((char*)d_ws + WS_ENORM);
  float*              embt  = (float*)((char*)d_ws + WS_EMBT);
  ushort* zh = (ushort*)((char*)d_ws + WS_ZH);
  ushort* zm = (ushort*)((char*)d_ws + WS_ZM);
  ushort* eh = (ushort*)((char*)d_ws + WS_EH);
  ushort* em = (ushort*)((char*)d_ws + WS_EM);
  (void)in_sizes; (void)n_in; (void)out_size; (void)ws_size;

  hipMemsetAsync(d_ws, 0, 128, stream);                                  // acc+cnt
  hipMemsetAsync((char*)d_ws + WS_KEYS, 0xFF, (size_t)NR * 8, stream);   // keys
  hipMemsetAsync((char*)d_ws + WS_RISK, 0xFF, (size_t)NR * 4, stream);   // rmin keys

  k_znorm    <<<NR / 256, 256, 0, stream>>>(z, znorm);
  k_enorm    <<<KCB / 4, 256, 0, stream>>>(emb, enorm);
  k_transpose<<<(KCB / 64) * (CD / 64), 256, 0, stream>>>(emb, embt);
  k_zsplit   <<<(NR / 256) * 16, 256, 0, stream>>>(z, zh, zm);
  k_esplit   <<<(KCB / 256) * 16, 256, 0, stream>>>(emb, eh, em);
  k_dist_mfma<<<256, 512, 3 * BUFB, stream>>>(zh, zm, eh, em,
                                              enorm, znorm, keys, risk);
  k_resolve  <<<NR / 256, 256, 0, stream>>>(keys, risk, idxA, list, cnt);
  k_rescan   <<<256, 256, 0, stream>>>(z, embt, enorm, znorm, list, cnt, idxA);
  k_gather   <<<NR / 16, 256, 0, stream>>>(z, emb, idxA, out, acc);
  k_loss     <<<1, 1, 0, stream>>>(acc, out);
}